// Round 2
// baseline (142.790 us; speedup 1.0000x reference)
//
#include <hip/hip_runtime.h>
#include <hip/hip_bf16.h>

// Problem constants (match reference)
#define N_OUT_ROWS 250000
#define CIN 32
#define COUT 64
#define KOCT 8
#define TILES (N_OUT_ROWS / 16)      // 15625 row-tiles of 16
#define WPB 4                        // waves per block
#define NBLK 1024                    // persistent: 4 blocks/CU * 256 CU
#define WAVES_TOTAL (NBLK * WPB)     // 4096
#define BN_EPS 1e-5f

typedef __attribute__((ext_vector_type(8))) short bf16x8;
typedef __attribute__((ext_vector_type(4))) float f32x4;

static __device__ __forceinline__ unsigned short f2bf(float f) {
  __hip_bfloat16 h = __float2bfloat16(f);
  unsigned short s;
  __builtin_memcpy(&s, &h, 2);
  return s;
}

// Fused gather + bf16-MFMA GEMM + BN partial stats.
// Persistent blocks: weights staged into LDS ONCE per block, then each wave
// grid-strides over 16-row output tiles. A fragments gathered directly from
// global (no LDS staging - no reuse exists). BN stats accumulate in registers
// across all tiles; one atomic phase per block at the end.
__global__ __launch_bounds__(256, 4)
void k_gemm(const float* __restrict__ x, const int* __restrict__ neigh,
            const float* __restrict__ w, float* __restrict__ out,
            float* __restrict__ stats) {
  __shared__ unsigned short Bt[COUT * 256];  // 32 KB, Bt[d][k*32+c] swizzled
  __shared__ float wpart[WPB][128];

  const int tid = threadIdx.x;

  // Stage weights once: w flat i = (k*32+c)*64 + d -> Bt[d][kc], XOR-swizzled.
  // float4 coalesced loads (16 iters instead of 64 scalar).
  #pragma unroll
  for (int it = 0; it < 16; ++it) {
    const int i = (it * 256 + tid) * 4;  // element index, i%4==0
    const float4 v = *reinterpret_cast<const float4*>(w + i);
    const int d = i & 63;                // d..d+3 stay within 0..63
    const int kc = i >> 6;
    const float vv[4] = {v.x, v.y, v.z, v.w};
    #pragma unroll
    for (int m = 0; m < 4; ++m) {
      int e = ((d + m) << 8) + kc;
      e ^= ((d + m) & 7) << 3;  // bank swizzle (element-level; <<4 in bytes)
      Bt[e] = f2bf(vv[m]);
    }
  }
  __syncthreads();

  const int lane = tid & 63;
  const int widx = tid >> 6;
  const int r  = lane & 15;   // A-frag row / C col-within-tile
  const int g4 = lane >> 4;   // k-slice group

  float sacc[4] = {0.f, 0.f, 0.f, 0.f};
  float qacc[4] = {0.f, 0.f, 0.f, 0.f};

  for (int tile = blockIdx.x * WPB + widx; tile < TILES; tile += WAVES_TOTAL) {
    const int n0 = tile << 4;
    const int nrow = n0 + r;
    const int4 nv0 = *reinterpret_cast<const int4*>(neigh + nrow * KOCT);
    const int4 nv1 = *reinterpret_cast<const int4*>(neigh + nrow * KOCT + 4);
    const int idx[KOCT] = {nv0.x, nv0.y, nv0.z, nv0.w,
                           nv1.x, nv1.y, nv1.z, nv1.w};

    // Issue ALL gather loads before any MFMA: max memory-level parallelism.
    float4 va[KOCT], vb[KOCT];
    #pragma unroll
    for (int kt = 0; kt < KOCT; ++kt) {
      const float* xr = x + idx[kt] * CIN + g4 * 8;
      va[kt] = *reinterpret_cast<const float4*>(xr);
      vb[kt] = *reinterpret_cast<const float4*>(xr + 4);
    }

    f32x4 acc[4];
    #pragma unroll
    for (int ct = 0; ct < 4; ++ct) acc[ct] = (f32x4){0.f, 0.f, 0.f, 0.f};

    #pragma unroll
    for (int kt = 0; kt < KOCT; ++kt) {
      union { bf16x8 v; __hip_bfloat162 h[4]; } af;
      af.h[0] = __float22bfloat162_rn(make_float2(va[kt].x, va[kt].y));
      af.h[1] = __float22bfloat162_rn(make_float2(va[kt].z, va[kt].w));
      af.h[2] = __float22bfloat162_rn(make_float2(vb[kt].x, vb[kt].y));
      af.h[3] = __float22bfloat162_rn(make_float2(vb[kt].z, vb[kt].w));
      #pragma unroll
      for (int ct = 0; ct < 4; ++ct) {
        int e = ((ct * 16 + r) << 8) + kt * 32 + g4 * 8;
        e ^= (r & 7) << 3;  // (ct*16+r)&7 == r&7
        const bf16x8 bfr = *reinterpret_cast<const bf16x8*>(&Bt[e]);
        acc[ct] = __builtin_amdgcn_mfma_f32_16x16x32_bf16(af.v, bfr, acc[ct], 0, 0, 0);
      }
    }

    // C write: col = ct*16 + r, row = g4*4 + j (m89-verified layout)
    const int rbase = n0 + g4 * 4;
    #pragma unroll
    for (int ct = 0; ct < 4; ++ct) {
      #pragma unroll
      for (int j = 0; j < 4; ++j)
        out[(rbase + j) * COUT + ct * 16 + r] = acc[ct][j];
      sacc[ct] += acc[ct][0] + acc[ct][1] + acc[ct][2] + acc[ct][3];
      qacc[ct] += acc[ct][0] * acc[ct][0] + acc[ct][1] * acc[ct][1] +
                  acc[ct][2] * acc[ct][2] + acc[ct][3] * acc[ct][3];
    }
  }

  // One stats-reduction per block (vs per-tile): shuffle across g4 groups,
  // combine waves in LDS, 128 atomics per block.
  #pragma unroll
  for (int ct = 0; ct < 4; ++ct) {
    sacc[ct] += __shfl_xor(sacc[ct], 16);
    qacc[ct] += __shfl_xor(qacc[ct], 16);
    sacc[ct] += __shfl_xor(sacc[ct], 32);
    qacc[ct] += __shfl_xor(qacc[ct], 32);
  }
  if (lane < 16) {
    #pragma unroll
    for (int ct = 0; ct < 4; ++ct) {
      wpart[widx][ct * 16 + lane] = sacc[ct];
      wpart[widx][64 + ct * 16 + lane] = qacc[ct];
    }
  }
  __syncthreads();
  if (tid < 128) {
    atomicAdd(&stats[tid], wpart[0][tid] + wpart[1][tid] +
                           wpart[2][tid] + wpart[3][tid]);
  }
}

// Finalize BN: y = (out - mean) * rsqrt(var+eps) * gamma + beta, in place.
__global__ __launch_bounds__(256)
void k_bn(float* __restrict__ out, const float* __restrict__ stats,
          const float* __restrict__ gamma, const float* __restrict__ beta) {
  __shared__ float sc[COUT], bs[COUT];
  if (threadIdx.x < COUT) {
    const int d = threadIdx.x;
    const float inv = 1.0f / (float)N_OUT_ROWS;
    const float mean = stats[d] * inv;
    const float var = stats[COUT + d] * inv - mean * mean;
    const float rstd = rsqrtf(var + BN_EPS);
    const float scale = rstd * gamma[d];
    sc[d] = scale;
    bs[d] = beta[d] - mean * scale;
  }
  __syncthreads();

  const int total4 = N_OUT_ROWS * COUT / 4;  // 4,000,000 float4s
  float4* o4 = reinterpret_cast<float4*>(out);
  for (int i = blockIdx.x * blockDim.x + threadIdx.x; i < total4;
       i += gridDim.x * blockDim.x) {
    const int d0 = (i & 15) << 2;  // 16 float4 per 64-ch row
    float4 v = o4[i];
    v.x = v.x * sc[d0]     + bs[d0];
    v.y = v.y * sc[d0 + 1] + bs[d0 + 1];
    v.z = v.z * sc[d0 + 2] + bs[d0 + 2];
    v.w = v.w * sc[d0 + 3] + bs[d0 + 3];
    o4[i] = v;
  }
}

extern "C" void kernel_launch(void* const* d_in, const int* in_sizes, int n_in,
                              void* d_out, int out_size, void* d_ws, size_t ws_size,
                              hipStream_t stream) {
  const float* x     = (const float*)d_in[0];
  const int*   neigh = (const int*)d_in[1];
  const float* w     = (const float*)d_in[2];
  const float* gamma = (const float*)d_in[3];
  const float* beta  = (const float*)d_in[4];
  float* out   = (float*)d_out;
  float* stats = (float*)d_ws;  // 128 floats: [0:64] sum, [64:128] sumsq

  hipMemsetAsync(stats, 0, 128 * sizeof(float), stream);
  k_gemm<<<NBLK, 256, 0, stream>>>(x, neigh, w, out, stats);
  k_bn<<<2048, 256, 0, stream>>>(out, stats, gamma, beta);
}

// Round 3
// 85.517 us; speedup vs baseline: 1.6697x; 1.6697x over previous
//
#include <hip/hip_runtime.h>
#include <hip/hip_bf16.h>

// Problem constants (match reference)
#define N_OUT_ROWS 250000
#define TILES 15625      // 16-row output tiles
#define NBLK 512         // 2 blocks/CU
#define WPB 4            // waves per block
#define NWAVES (NBLK * WPB)  // 2048
#define BN_EPS 1e-5f

typedef __attribute__((ext_vector_type(8))) short bf16x8;
typedef __attribute__((ext_vector_type(8))) unsigned short u16x8;
typedef __attribute__((ext_vector_type(4))) float f32x4;

static __device__ __forceinline__ unsigned short f2bf(float f) {
  // round-to-nearest-even f32 -> bf16 bits
  union { float f; unsigned u; } v; v.f = f;
  unsigned r = v.u + 0x7FFFu + ((v.u >> 16) & 1u);
  return (unsigned short)(r >> 16);
}

// Fire-and-forget 16B gather into LDS (per-lane global src, linear LDS dest:
// uniform base + lane*16). Tracked by vmcnt; costs zero VGPRs for data.
#define GLOAD_LDS16(gsrc, ldst)                                                \
  __builtin_amdgcn_global_load_lds(                                            \
      (const __attribute__((address_space(1))) unsigned int*)(gsrc),           \
      (__attribute__((address_space(3))) unsigned int*)(ldst), 16, 0, 0)

// Prep: convert weights f32 -> bf16 fragment-ready layout in d_ws, zero stats.
// bfrag[((kt*4+ct)*64 + lane)*8 + j] = bf16(w[(kt*32 + g4*8 + j)*64 + ct*16 + r])
__global__ void k_prep(const float* __restrict__ w,
                       unsigned short* __restrict__ bfrag,
                       float* __restrict__ stats) {
  const int i = blockIdx.x * 256 + threadIdx.x;  // 0..2047
  if (i < 128) stats[i] = 0.f;
  const int f = i >> 6, l = i & 63;
  const int kt = f >> 2, ct = f & 3, rr = l & 15, gg = l >> 4;
  u16x8 o;
  #pragma unroll
  for (int j = 0; j < 8; ++j)
    o[j] = f2bf(w[(kt * 32 + gg * 8 + j) * 64 + ct * 16 + rr]);
  *reinterpret_cast<u16x8*>(bfrag + i * 8) = o;
}

// Fused gather + bf16-MFMA GEMM + BN partial stats.
// Per wave: B fully in registers (32 frags = 128 VGPR), A gathered per tile
// via 16 global_load_lds into a private 16KB LDS buffer (deep vmcnt queue ->
// high MLP without VGPR pressure). 2 blocks/CU, 2 waves/SIMD for TLP.
__global__ __launch_bounds__(256, 2)
void k_gemm(const float* __restrict__ x, const int* __restrict__ neigh,
            const unsigned short* __restrict__ bfrag, float* __restrict__ out,
            float* __restrict__ stats) {
  __shared__ __align__(16) unsigned char Abuf_all[WPB][16384];
  __shared__ float wpart[WPB][128];

  const int tid = threadIdx.x;
  const int lane = tid & 63;
  const int widx = tid >> 6;
  unsigned char* Abuf = Abuf_all[widx];

  // Load all B fragments into registers (compile-time indexed -> stays in VGPR).
  bf16x8 bf[8][4];
  #pragma unroll
  for (int kt = 0; kt < 8; ++kt)
    #pragma unroll
    for (int ct = 0; ct < 4; ++ct)
      bf[kt][ct] = *reinterpret_cast<const bf16x8*>(
          bfrag + ((kt * 4 + ct) * 64 + lane) * 8);

  // Contiguous tile range per wave (sequential neigh reads).
  const int gw = blockIdx.x * WPB + widx;  // 0..2047
  const int q = TILES / NWAVES;            // 7
  const int rem = TILES % NWAVES;          // 1289
  const int start = (gw < rem) ? gw * (q + 1) : rem * (q + 1) + (gw - rem) * q;
  const int cnt = q + (gw < rem ? 1 : 0);

  const int r = lane & 15;     // A row within tile / C col-within-group
  const int g4 = lane >> 4;    // k-slice group
  const int seg = lane & 7;    // gather: 16B segment within a 128B x-row
  const int ktl = lane >> 3;   // gather: which neighbor this lane fetches
  const int swz = (r & 7) << 4;
  const int rdbase = (r << 10) + (g4 << 5);

  float sacc[4] = {0.f, 0.f, 0.f, 0.f};
  float qacc[4] = {0.f, 0.f, 0.f, 0.f};

  for (int k = 0; k < cnt; ++k) {
    const int t = start + k;
    const int n0 = t << 4;

    // Neighbor indices: idxv[m] = m-th row's ktl-th neighbor (broadcast reads).
    int idxv[16];
    #pragma unroll
    for (int m = 0; m < 16; ++m)
      idxv[m] = neigh[(n0 + m) * 8 + ktl];

    // WAR guard: previous tile's ds_reads fully retired before overwriting.
    asm volatile("s_waitcnt lgkmcnt(0)" ::: "memory");
    __builtin_amdgcn_sched_barrier(0);

    // 16 gathers: instr j stages output-row j's 8 neighbor rows (1KB).
    // Source segment pre-permuted (seg ^ (j&7)) so the linear LDS write is
    // the XOR-swizzled layout the ds_reads below expect (Rule 21).
    #pragma unroll
    for (int j = 0; j < 16; ++j) {
      const float* src = x + (size_t)idxv[j] * 32 + ((seg ^ (j & 7)) * 4);
      GLOAD_LDS16(src, Abuf + j * 1024);
    }

    // Drain the gather queue (also drains prior stores/idx loads - harmless).
    asm volatile("s_waitcnt vmcnt(0)" ::: "memory");
    __builtin_amdgcn_sched_barrier(0);

    f32x4 acc[4];
    #pragma unroll
    for (int ct = 0; ct < 4; ++ct) acc[ct] = (f32x4){0.f, 0.f, 0.f, 0.f};

    #pragma unroll
    for (int kt = 0; kt < 8; ++kt) {
      const int o0 = rdbase + (kt << 7);
      const f32x4 a0 = *reinterpret_cast<const f32x4*>(Abuf + (o0 ^ swz));
      const f32x4 a1 = *reinterpret_cast<const f32x4*>(Abuf + ((o0 + 16) ^ swz));
      union { bf16x8 v; __hip_bfloat162 h[4]; } af;
      af.h[0] = __float22bfloat162_rn(make_float2(a0[0], a0[1]));
      af.h[1] = __float22bfloat162_rn(make_float2(a0[2], a0[3]));
      af.h[2] = __float22bfloat162_rn(make_float2(a1[0], a1[1]));
      af.h[3] = __float22bfloat162_rn(make_float2(a1[2], a1[3]));
      #pragma unroll
      for (int ct = 0; ct < 4; ++ct)
        acc[ct] = __builtin_amdgcn_mfma_f32_16x16x32_bf16(af.v, bf[kt][ct],
                                                          acc[ct], 0, 0, 0);
    }

    // C write: col = ct*16 + r, row = g4*4 + j (m89-verified layout)
    const int rbase = n0 + g4 * 4;
    #pragma unroll
    for (int ct = 0; ct < 4; ++ct) {
      #pragma unroll
      for (int j = 0; j < 4; ++j)
        out[(rbase + j) * 64 + ct * 16 + r] = acc[ct][j];
      sacc[ct] += acc[ct][0] + acc[ct][1] + acc[ct][2] + acc[ct][3];
      qacc[ct] += acc[ct][0] * acc[ct][0] + acc[ct][1] * acc[ct][1] +
                  acc[ct][2] * acc[ct][2] + acc[ct][3] * acc[ct][3];
    }
  }

  // Block-level BN stats reduction: shuffle across g4 groups, LDS combine,
  // 128 atomics per block.
  #pragma unroll
  for (int ct = 0; ct < 4; ++ct) {
    sacc[ct] += __shfl_xor(sacc[ct], 16);
    qacc[ct] += __shfl_xor(qacc[ct], 16);
    sacc[ct] += __shfl_xor(sacc[ct], 32);
    qacc[ct] += __shfl_xor(qacc[ct], 32);
  }
  if (lane < 16) {
    #pragma unroll
    for (int ct = 0; ct < 4; ++ct) {
      wpart[widx][ct * 16 + lane] = sacc[ct];
      wpart[widx][64 + ct * 16 + lane] = qacc[ct];
    }
  }
  __syncthreads();
  if (tid < 128) {
    atomicAdd(&stats[tid], wpart[0][tid] + wpart[1][tid] +
                           wpart[2][tid] + wpart[3][tid]);
  }
}

// Finalize BN: y = (out - mean) * rsqrt(var+eps) * gamma + beta, in place.
__global__ __launch_bounds__(256)
void k_bn(float* __restrict__ out, const float* __restrict__ stats,
          const float* __restrict__ gamma, const float* __restrict__ beta) {
  __shared__ float sc[64], bs[64];
  if (threadIdx.x < 64) {
    const int d = threadIdx.x;
    const float inv = 1.0f / (float)N_OUT_ROWS;
    const float mean = stats[d] * inv;
    const float var = stats[64 + d] * inv - mean * mean;
    const float rstd = rsqrtf(var + BN_EPS);
    const float scale = rstd * gamma[d];
    sc[d] = scale;
    bs[d] = beta[d] - mean * scale;
  }
  __syncthreads();

  const int total4 = N_OUT_ROWS * 64 / 4;  // 4,000,000 float4s
  float4* o4 = reinterpret_cast<float4*>(out);
  for (int i = blockIdx.x * blockDim.x + threadIdx.x; i < total4;
       i += gridDim.x * blockDim.x) {
    const int d0 = (i & 15) << 2;
    float4 v = o4[i];
    v.x = v.x * sc[d0]     + bs[d0];
    v.y = v.y * sc[d0 + 1] + bs[d0 + 1];
    v.z = v.z * sc[d0 + 2] + bs[d0 + 2];
    v.w = v.w * sc[d0 + 3] + bs[d0 + 3];
    o4[i] = v;
  }
}

extern "C" void kernel_launch(void* const* d_in, const int* in_sizes, int n_in,
                              void* d_out, int out_size, void* d_ws, size_t ws_size,
                              hipStream_t stream) {
  const float* x     = (const float*)d_in[0];
  const int*   neigh = (const int*)d_in[1];
  const float* w     = (const float*)d_in[2];
  const float* gamma = (const float*)d_in[3];
  const float* beta  = (const float*)d_in[4];
  float* out = (float*)d_out;

  float* stats = (float*)d_ws;                              // 128 f32
  unsigned short* bfrag = (unsigned short*)((char*)d_ws + 1024);  // 32 KB

  k_prep<<<8, 256, 0, stream>>>(w, bfrag, stats);
  k_gemm<<<NBLK, 256, 0, stream>>>(x, neigh, bfrag, out, stats);
  k_bn<<<2048, 256, 0, stream>>>(out, stats, gamma, beta);
}